// Round 1
// 1695.275 us; speedup vs baseline: 1.2730x; 1.2730x over previous
//
#include <hip/hip_runtime.h>
#include <stdint.h>

// C[M,N] = A[M,K] * W[N,K]^T + bias;  M=8192 (seq*batch), N=16384, K=4096
#define M_DIM 8192
#define N_DIM 16384
#define K_DIM 4096

// 256x256 8-phase template (m201): BK=64, 8 waves (2M x 4N), 128 KiB LDS dbuf
#define BM 256
#define BN 256
#define BK 64
#define NT (K_DIM / BK)                      // 64 K-tiles
#define NWG ((M_DIM / BM) * (N_DIM / BN))    // 32*64 = 2048 workgroups

typedef __bf16   bf16x8 __attribute__((ext_vector_type(8)));
typedef float    f32x4  __attribute__((ext_vector_type(4)));
typedef uint16_t u16x8  __attribute__((ext_vector_type(8)));

__device__ __forceinline__ uint16_t f2bf(float f) {
    union { float f; uint32_t u; } v; v.f = f;
    uint32_t u = v.u;
    return (uint16_t)((u + 0x7FFFu + ((u >> 16) & 1u)) >> 16);  // RNE bf16
}

// f32 -> bf16 conversion, vectorized 4-wide, grid-stride
__global__ void __launch_bounds__(256) cvt_kernel(const float* __restrict__ src,
                                                  uint16_t* __restrict__ dst, int n4) {
    int i = blockIdx.x * 256 + threadIdx.x;
    const int stride = gridDim.x * 256;
    for (; i < n4; i += stride) {
        float4 f = ((const float4*)src)[i];
        ushort4 o = make_ushort4(f2bf(f.x), f2bf(f.y), f2bf(f.z), f2bf(f.w));
        ((ushort4*)dst)[i] = o;
    }
}

// async global->LDS, 16B per lane; LDS dest must be linear in lane order.
__device__ __forceinline__ void gload16(const uint16_t* g, uint16_t* lds) {
    __builtin_amdgcn_global_load_lds(
        (const __attribute__((address_space(1))) uint32_t*)g,
        (__attribute__((address_space(3))) uint32_t*)lds, 16, 0, 0);
}

// fallback staging: load 8 f32, convert, one ds_write_b128
__device__ __forceinline__ void stage_cvt(const float* __restrict__ g, uint16_t* lds) {
    float4 f0 = *(const float4*)g;
    float4 f1 = *(const float4*)(g + 4);
    u16x8 o;
    o[0] = f2bf(f0.x); o[1] = f2bf(f0.y); o[2] = f2bf(f0.z); o[3] = f2bf(f0.w);
    o[4] = f2bf(f1.x); o[5] = f2bf(f1.y); o[6] = f2bf(f1.z); o[7] = f2bf(f1.w);
    *(u16x8*)lds = o;
}

// ---------------------------------------------------------------------------
// 256^2 8-phase GEMM.
//
// LDS layout per tile: [256 rows][64 k] bf16, XOR-swizzled: the 16B chunk at
// logical (row, c16) lives at slot c16 ^ (row & 7).  global_load_lds writes
// linearly (rule 21), so the *global source* is inverse-swizzled per lane and
// the ds_read applies the same XOR.  Kills the 16-way bank conflict.
//
// Per K-tile: 4 phases = C-quadrants (mh,nh) in order (0,0),(0,1),(1,0),(1,1).
//   reads:  phase0 = A(mh=0) 8x b128 + B(all) 8x b128 ; phase2 = A(mh=1) 8x.
//   stage:  ph0 -> A-bot(kt+1) [other buf], ph1 -> B-top(kt+2),
//           ph2 -> B-bot(kt+2), ph3 -> A-top(kt+2)   [same buf as kt: safe
//           because all B reads drain at ph0 (explicit lgkmcnt(0)) and all A
//           reads drain by ph2's MFMA operand waits, before those stages issue].
//   vmcnt(6) once per K-tile (3 half-tiles in flight); vmcnt(0) at kt==NT-2.
// ---------------------------------------------------------------------------

#define STAGE(part, kts) do {                                                  \
    const int _b = (kts) & 1;                                                  \
    const int _k = (kts) * BK;                                                 \
    if ((part) >= 2) {                                                         \
        const int _h = (part) - 2;                                             \
        const uint16_t* _g = pA + (size_t)_h * 128 * K_DIM + _k;               \
        gload16(_g,                &As[_b][_h * 8192 + tid * 8]);              \
        gload16(_g + 64 * K_DIM,   &As[_b][_h * 8192 + tid * 8 + 4096]);       \
    } else {                                                                   \
        const int _h = (part);                                                 \
        const uint16_t* _g = pB + (size_t)_h * 128 * K_DIM + _k;               \
        gload16(_g,                &Bs[_b][_h * 8192 + tid * 8]);              \
        gload16(_g + 64 * K_DIM,   &Bs[_b][_h * 8192 + tid * 8 + 4096]);       \
    }                                                                          \
} while (0)

#define MFMA_Q(mh, nh)                                                         \
    _Pragma("unroll")                                                          \
    for (int t = 0; t < 4; ++t) {                                              \
        _Pragma("unroll")                                                      \
        for (int u = 0; u < 2; ++u) {                                          \
            acc[(mh)*4 + t][(nh)*2 + u] = __builtin_amdgcn_mfma_f32_16x16x32_bf16( \
                a[t][0], bfr[(nh)*2 + u][0], acc[(mh)*4 + t][(nh)*2 + u], 0, 0, 0); \
            acc[(mh)*4 + t][(nh)*2 + u] = __builtin_amdgcn_mfma_f32_16x16x32_bf16( \
                a[t][1], bfr[(nh)*2 + u][1], acc[(mh)*4 + t][(nh)*2 + u], 0, 0, 0); \
        }                                                                      \
    }

#define BARRIER() asm volatile("s_barrier" ::: "memory")

__global__ void __launch_bounds__(512, 2)
gemm256_kernel(const uint16_t* __restrict__ Ag, const uint16_t* __restrict__ Bg,
               const float* __restrict__ bias, float* __restrict__ C) {
    __shared__ alignas(16) uint16_t As[2][BM * BK];   // 64 KiB
    __shared__ alignas(16) uint16_t Bs[2][BN * BK];   // 64 KiB

    const int tid  = threadIdx.x;
    const int lane = tid & 63;
    const int wave = tid >> 6;
    const int wr   = wave >> 2;   // 0..1 -> 128-row half of the tile
    const int wc   = wave & 3;    // 0..3 -> 64-col quarter

    // XCD-aware swizzle: 2048 wgs, 8 XCDs, 256 contiguous per XCD (bijective).
    const int lid = blockIdx.x;
    const int swz = (lid & 7) * (NWG / 8) + (lid >> 3);
    const long n0 = (long)(swz & 63) * BN;
    const long m0 = (long)(swz >> 6) * BM;

    // --- staging geometry: chunk c=tid (rows 0..63) and c=tid+512 (rows 64..127)
    // of each 128x64 half-tile; global col pre-swizzled so linear LDS = swizzled.
    const int r0 = tid >> 3;                              // row within half-tile
    const int sw = ((tid & 7) ^ (r0 & 7)) * 8;            // swizzled k-offset (elems)
    const uint16_t* pA = Ag + (size_t)(m0 + r0) * K_DIM + sw;
    const uint16_t* pB = Bg + (size_t)(n0 + r0) * K_DIM + sw;

    // --- fragment read geometry (16x16x32: A[m=lane&15][k=(lane>>4)*8+j])
    const int frow = lane & 15;
    const int fx   = lane >> 4;
    const int sx   = frow & 7;
    const int swr0 = ((0 + fx) ^ sx) * 8;   // ks=0 swizzled chunk
    const int swr1 = ((4 + fx) ^ sx) * 8;   // ks=1 swizzled chunk
    const int arow = wr * 128 + frow;
    const int brow = wc * 64  + frow;

    // --- prologue: stage kt0 fully + kt1 parts {B-top,B-bot,A-top} = 7 half-tiles
    STAGE(0, 0); STAGE(1, 0); STAGE(2, 0); STAGE(3, 0);
    STAGE(0, 1); STAGE(1, 1); STAGE(2, 1);

    f32x4 acc[8][4];
    const f32x4 fzero = {0.f, 0.f, 0.f, 0.f};
#pragma unroll
    for (int i = 0; i < 8; ++i)
#pragma unroll
        for (int j = 0; j < 4; ++j) acc[i][j] = fzero;

    asm volatile("s_waitcnt vmcnt(6)" ::: "memory");   // kt0 landed, 3 ht in flight
    BARRIER();

#pragma unroll 2
    for (int kt = 0; kt < NT; ++kt) {
        const int buf = kt & 1;
        const uint16_t* Ab = As[buf];
        const uint16_t* Bb = Bs[buf];
        bf16x8 a[4][2], bfr[4][2];

        // ---- phase 0: Q(0,0).  reads A(mh=0) + B(all); stage A-bot of kt+1.
#pragma unroll
        for (int t = 0; t < 4; ++t) {
            const uint16_t* p = Ab + (arow + t * 16) * BK;
            a[t][0] = *(const bf16x8*)(p + swr0);
            a[t][1] = *(const bf16x8*)(p + swr1);
        }
#pragma unroll
        for (int n = 0; n < 4; ++n) {
            const uint16_t* p = Bb + (brow + n * 16) * BK;
            bfr[n][0] = *(const bf16x8*)(p + swr0);
            bfr[n][1] = *(const bf16x8*)(p + swr1);
        }
        if (kt + 1 < NT) STAGE(3, kt + 1);
        BARRIER();
        __builtin_amdgcn_s_setprio(1);
        MFMA_Q(0, 0);
        __builtin_amdgcn_s_setprio(0);
        // REQUIRED: drain B(nh=1) reads (not consumed until phase 1) before the
        // barrier that allows phase-1's B-top staging to issue.
        asm volatile("s_waitcnt lgkmcnt(0)" ::: "memory");
        BARRIER();

        // ---- phase 1: Q(0,1).  no reads; stage B-top of kt+2.
        if (kt + 2 < NT) STAGE(0, kt + 2);
        BARRIER();
        __builtin_amdgcn_s_setprio(1);
        MFMA_Q(0, 1);
        __builtin_amdgcn_s_setprio(0);
        BARRIER();

        // ---- phase 2: Q(1,0).  reads A(mh=1); stage B-bot of kt+2.
#pragma unroll
        for (int t = 0; t < 4; ++t) {
            const uint16_t* p = Ab + (arow + 64 + t * 16) * BK;
            a[t][0] = *(const bf16x8*)(p + swr0);
            a[t][1] = *(const bf16x8*)(p + swr1);
        }
        if (kt + 2 < NT) STAGE(1, kt + 2);
        BARRIER();
        __builtin_amdgcn_s_setprio(1);
        MFMA_Q(1, 0);   // consumes all 8 A reads -> drained before cluster ends
        __builtin_amdgcn_s_setprio(0);
        BARRIER();

        // ---- phase 3: Q(1,1).  no reads; stage A-top of kt+2; counted vmcnt.
        if (kt + 2 < NT) STAGE(2, kt + 2);
        BARRIER();
        __builtin_amdgcn_s_setprio(1);
        MFMA_Q(1, 1);
        __builtin_amdgcn_s_setprio(0);
        if (kt < NT - 2) asm volatile("s_waitcnt vmcnt(6)" ::: "memory");
        else             asm volatile("s_waitcnt vmcnt(0)" ::: "memory");
        BARRIER();
    }

    // ---- epilogue: C/D layout col=lane&15, row=(lane>>4)*4+reg
    const int cr = fx * 4;
    float bb[4];
#pragma unroll
    for (int n = 0; n < 4; ++n) bb[n] = bias[n0 + wc * 64 + n * 16 + frow];
#pragma unroll
    for (int mf = 0; mf < 8; ++mf) {
        const long grow = m0 + wr * 128 + mf * 16 + cr;
#pragma unroll
        for (int nf = 0; nf < 4; ++nf) {
            const long gcol = n0 + wc * 64 + nf * 16 + frow;
#pragma unroll
            for (int r = 0; r < 4; ++r)
                C[(grow + r) * N_DIM + gcol] = acc[mf][nf][r] + bb[nf];
        }
    }
}

// ---------------------------------------------------------------------------
// Fallback (workspace too small): 128^2 m97-structure with inline f32->bf16.
// ---------------------------------------------------------------------------
__global__ void __launch_bounds__(256, 2)
gemm_fb(const float* __restrict__ Ap, const float* __restrict__ Bp,
        const float* __restrict__ bias, float* __restrict__ C) {
    __shared__ alignas(16) uint16_t Asf[128 * 32];
    __shared__ alignas(16) uint16_t Bsf[128 * 32];

    const int tid  = threadIdx.x;
    const int lane = tid & 63;
    const int wave = tid >> 6;
    const int wr   = wave >> 1;
    const int wc   = wave & 1;
    const long m0  = (long)blockIdx.y * 128;
    const long n0  = (long)blockIdx.x * 128;

    const int c1  = tid + 256;
    const int ar0 = tid >> 2, ac0 = (tid & 3) * 8;
    const int ar1 = c1 >> 2,  ac1 = (c1 & 3) * 8;

    f32x4 acc[4][4];
    const f32x4 fzero = {0.f, 0.f, 0.f, 0.f};
#pragma unroll
    for (int i = 0; i < 4; ++i)
#pragma unroll
        for (int j = 0; j < 4; ++j) acc[i][j] = fzero;

    const int frow = lane & 15;
    const int fk   = (lane >> 4) * 8;

    for (int k0 = 0; k0 < K_DIM; k0 += 32) {
        stage_cvt(Ap + (m0 + ar0) * K_DIM + k0 + ac0, &Asf[tid * 8]);
        stage_cvt(Ap + (m0 + ar1) * K_DIM + k0 + ac1, &Asf[c1 * 8]);
        stage_cvt(Bp + (n0 + ar0) * K_DIM + k0 + ac0, &Bsf[tid * 8]);
        stage_cvt(Bp + (n0 + ar1) * K_DIM + k0 + ac1, &Bsf[c1 * 8]);
        __syncthreads();

        bf16x8 af[4], bfr[4];
#pragma unroll
        for (int t = 0; t < 4; ++t) {
            af[t]  = *(const bf16x8*)&Asf[(wr * 64 + t * 16 + frow) * 32 + fk];
            bfr[t] = *(const bf16x8*)&Bsf[(wc * 64 + t * 16 + frow) * 32 + fk];
        }
#pragma unroll
        for (int i = 0; i < 4; ++i)
#pragma unroll
            for (int j = 0; j < 4; ++j)
                acc[i][j] = __builtin_amdgcn_mfma_f32_16x16x32_bf16(
                    af[i], bfr[j], acc[i][j], 0, 0, 0);
        __syncthreads();
    }

    const int cr = (lane >> 4) * 4;
    const int cc = lane & 15;
    float bb[4];
#pragma unroll
    for (int j = 0; j < 4; ++j) bb[j] = bias[n0 + wc * 64 + j * 16 + cc];
#pragma unroll
    for (int i = 0; i < 4; ++i) {
        const long grow = m0 + wr * 64 + i * 16 + cr;
#pragma unroll
        for (int j = 0; j < 4; ++j) {
            const long gcol = n0 + wc * 64 + j * 16 + cc;
#pragma unroll
            for (int r = 0; r < 4; ++r)
                C[(grow + r) * N_DIM + gcol] = acc[i][j][r] + bb[j];
        }
    }
}

extern "C" void kernel_launch(void* const* d_in, const int* in_sizes, int n_in,
                              void* d_out, int out_size, void* d_ws, size_t ws_size,
                              hipStream_t stream) {
    const float* x    = (const float*)d_in[0];
    const float* w    = (const float*)d_in[1];
    const float* bias = (const float*)d_in[2];
    float* out        = (float*)d_out;

    const size_t xe   = (size_t)M_DIM * K_DIM;
    const size_t we   = (size_t)N_DIM * K_DIM;
    const size_t need = (xe + we) * sizeof(uint16_t);   // 192 MiB

    if (ws_size >= need) {
        uint16_t* xb = (uint16_t*)d_ws;
        uint16_t* wb = xb + xe;
        cvt_kernel<<<4096, 256, 0, stream>>>(x, xb, (int)(xe / 4));
        cvt_kernel<<<8192, 256, 0, stream>>>(w, wb, (int)(we / 4));
        gemm256_kernel<<<dim3(NWG), dim3(512), 0, stream>>>(xb, wb, bias, out);
    } else {
        dim3 grid(N_DIM / 128, M_DIM / 128);
        gemm_fb<<<grid, 256, 0, stream>>>(x, w, bias, out);
    }
}